// Round 13
// baseline (147.918 us; speedup 1.0000x reference)
//
#include <hip/hip_runtime.h>
#include <hip/hip_fp16.h>

// CSPN: affinity conv -> 8 a-planes fp16 AoS (16 B/px) -> 24 diffusion steps
// fused T=6/launch. Round-11 structure (4-px threads, c1 register carry),
// launch_bounds(512,8) for 4 blocks/CU. Gen kernel vectorized 4 px/thread.
constexpr int B = 8, H = 512, W = 512;
constexpr int N = B * H * W;       // 2,097,152
constexpr int HW = H * W;

constexpr int TT = 32;             // output tile side
constexpr int T  = 6;              // fused steps per launch (24 = 4*6)
constexpr int XR = TT + 2 * T;     // 44: staged X region side
constexpr int XE = XR * XR;        // 1936 floats per buffer
constexpr int NG = XR / 4;         // 11 col-groups per row
constexpr int CR = XR - 2;         // 42 computed rows (xi = 1..42)
constexpr int NGT = CR * NG;       // 462 active threads
constexpr int NTH = H / TT, NTW = W / TT;   // 16 x 16
constexpr int NTILES = B * NTH * NTW;       // 2048 (div by 8 -> bijective swz)
constexpr int NT = 512;

// ---------------------------------------------------------------------------
// Kernel 1: affinity conv (1->8, 3x3 SAME) + bias -> normalize -> fp16 AoS.
// 4 px/thread: rows i-1..i+1 x cols j0-1..j0+4 loaded as float4 + 2 scalars.
// ---------------------------------------------------------------------------
__global__ __launch_bounds__(256) void cspn_gen_kernel(
    const float* __restrict__ x, const float* __restrict__ Wa,
    const float* __restrict__ ba, __half* __restrict__ Kh) {
  int t = blockIdx.x * 256 + threadIdx.x;     // N/4 threads
  int j0 = (t & (W / 4 - 1)) * 4;             // 0..508 step 4
  int i  = (t >> 7) & (H - 1);
  int b  = t >> 16;
  const float* xb = x + (size_t)b * HW;

  float rv[3][6];
#pragma unroll
  for (int r = 0; r < 3; ++r) {
    int ii = i - 1 + r;
    if ((unsigned)ii < (unsigned)H) {
      const float* row = xb + (size_t)ii * W;
      float4 c = *reinterpret_cast<const float4*>(row + j0);
      rv[r][1] = c.x; rv[r][2] = c.y; rv[r][3] = c.z; rv[r][4] = c.w;
      rv[r][0] = (j0 > 0) ? row[j0 - 1] : 0.f;
      rv[r][5] = (j0 + 4 < W) ? row[j0 + 4] : 0.f;
    } else {
#pragma unroll
      for (int q = 0; q < 6; ++q) rv[r][q] = 0.f;
    }
  }

  __half* Kp = Kh + ((size_t)b * HW + (size_t)i * W + j0) * 8;
#pragma unroll
  for (int p = 0; p < 4; ++p) {
    float aff[8];
    float abs_sum = 0.f;
#pragma unroll
    for (int c = 0; c < 8; ++c) {
      float a = ba[c];
#pragma unroll
      for (int u = 0; u < 3; ++u)
#pragma unroll
        for (int q = 0; q < 3; ++q)
          a += rv[u][p + q] * Wa[c * 9 + u * 3 + q];
      aff[c] = a;
      abs_sum += fabsf(a);
    }
    float inv = 1.0f / abs_sum;
    union { uint4 u; __half2 h[4]; } pk;
#pragma unroll
    for (int c = 0; c < 4; ++c)
      pk.h[c] = __floats2half2_rn(aff[2 * c] * inv, aff[2 * c + 1] * inv);
    *reinterpret_cast<uint4*>(Kp + (size_t)p * 8) = pk.u;
  }
}

// ---------------------------------------------------------------------------
// Kernel 2: T=6 fused steps, 32x32 tile, X region 44x44 double-buffered.
// Thread owns 4-px group (xi, xj0..+3): K packed fp16 (16 half2 + 4 fp32 K0);
// own 4 px ride in c1 between steps. launch_bounds(512,8): VGPR<=64 targeting
// 4 blocks/CU (32 waves). If this spills, revert to (512,6).
// ---------------------------------------------------------------------------
#define H2F(h) __half2float(h)

__global__ __launch_bounds__(NT, 8) void cspn_fused(
    const float* __restrict__ xin, const __half* __restrict__ Kh,
    float* __restrict__ xout) {
  __shared__ __align__(16) float sBuf[64 + 2 * XE + 64];  // front/back guards
  float* sX = sBuf + 64;

  int bid = blockIdx.x;
  int wg = (bid & 7) * (NTILES / 8) + (bid >> 3);  // XCD-chunked swizzle
  int b  = wg / (NTH * NTW);
  int rr = wg % (NTH * NTW);
  int ti0 = (rr / NTW) * TT, tj0 = (rr % NTW) * TT;
  int tid = threadIdx.x;

  bool active = tid < NGT;
  int xi  = 1 + tid / NG;          // 1..42
  int xj0 = (tid % NG) * 4;        // 0,4,...,40

  // ---- one-time K fragment: 4 px x half8, kept PACKED (16 half2 regs) ----
  __half2 kh[4][4];
  float4 k0;
  {
    int gi  = ti0 + xi - T;
    int gj0 = tj0 + xj0 - T;
    bool rowv = active && (unsigned)gi < (unsigned)H;
    const __half* Kb =
        Kh + ((size_t)b * HW + (size_t)(rowv ? gi : 0) * W) * 8;
    float k0v[4];
#pragma unroll
    for (int p = 0; p < 4; ++p) {
      int gj = gj0 + p;
      union { uint4 u; __half2 h[4]; } pk;
      pk.u = make_uint4(0u, 0u, 0u, 0u);
      if (rowv && (unsigned)gj < (unsigned)W)
        pk.u = *reinterpret_cast<const uint4*>(Kb + (size_t)gj * 8);
      float2 f01 = __half22float2(pk.h[0]);
      float2 f23 = __half22float2(pk.h[1]);
      float2 f45 = __half22float2(pk.h[2]);
      float2 f67 = __half22float2(pk.h[3]);
      k0v[p] = 1.0f - (f01.x + f01.y + f23.x + f23.y +
                       f45.x + f45.y + f67.x + f67.y);
      kh[p][0] = pk.h[0]; kh[p][1] = pk.h[1];
      kh[p][2] = pk.h[2]; kh[p][3] = pk.h[3];
    }
    k0 = make_float4(k0v[0], k0v[1], k0v[2], k0v[3]);
  }

  // ---- zero LDS guards + buf1 border rows (never computed) ----
  if (tid < 64) {
    sBuf[tid] = 0.f;
    sBuf[64 + 2 * XE + tid] = 0.f;
  }
  if (tid < 2 * XR) {              // buf1 rows 0 and 43
    int r = (tid < XR) ? 0 : (XR - 1);
    int c = (tid < XR) ? tid : tid - XR;
    sX[XE + r * XR + c] = 0.f;
  }

  // ---- stage X region into buf0 (float2-vectorized) ----
  const float* xb = xin + (size_t)b * HW;
  for (int p = tid; p < XR * (XR / 2); p += NT) {   // 968 float2
    int li = p / (XR / 2), g = p - li * (XR / 2);
    int gi = ti0 + li - T, gj = tj0 + 2 * g - T;
    float2 v = make_float2(0.f, 0.f);
    if ((unsigned)gi < (unsigned)H && (unsigned)gj < (unsigned)W)
      v = *reinterpret_cast<const float2*>(xb + gi * W + gj);
    *reinterpret_cast<float2*>(sX + li * XR + 2 * g) = v;
  }
  __syncthreads();

  // ---- T fused steps; own 4 px live in c1 ----
  int base = xi * XR + xj0;
  float4 c1;
  if (active) c1 = *reinterpret_cast<const float4*>(sX + base);
#pragma unroll
  for (int s = 0; s < T; ++s) {
    const float* Xc = sX + (s & 1) * XE;
    float* Xn = sX + (((s & 1) ^ 1)) * XE;
    if (active) {
      const float* rm = Xc + base - XR;
      const float* rp = Xc + base + XR;
      float4 c0 = *reinterpret_cast<const float4*>(rm);
      float  l0 = rm[-1], r0 = rm[4];
      float4 c2 = *reinterpret_cast<const float4*>(rp);
      float  l2 = rp[-1], r2 = rp[4];
      float  l1 = Xc[base - 1], r1 = Xc[base + 4];
      float4 acc;
      acc.x = k0.x * c1.x
            + H2F(kh[0][0].x) * l1   + H2F(kh[0][0].y) * c1.y
            + H2F(kh[0][1].x) * c0.x + H2F(kh[0][1].y) * l0
            + H2F(kh[0][2].x) * c0.y + H2F(kh[0][2].y) * c2.x
            + H2F(kh[0][3].x) * l2   + H2F(kh[0][3].y) * c2.y;
      acc.y = k0.y * c1.y
            + H2F(kh[1][0].x) * c1.x + H2F(kh[1][0].y) * c1.z
            + H2F(kh[1][1].x) * c0.y + H2F(kh[1][1].y) * c0.x
            + H2F(kh[1][2].x) * c0.z + H2F(kh[1][2].y) * c2.y
            + H2F(kh[1][3].x) * c2.x + H2F(kh[1][3].y) * c2.z;
      acc.z = k0.z * c1.z
            + H2F(kh[2][0].x) * c1.y + H2F(kh[2][0].y) * c1.w
            + H2F(kh[2][1].x) * c0.z + H2F(kh[2][1].y) * c0.y
            + H2F(kh[2][2].x) * c0.w + H2F(kh[2][2].y) * c2.z
            + H2F(kh[2][3].x) * c2.y + H2F(kh[2][3].y) * c2.w;
      acc.w = k0.w * c1.w
            + H2F(kh[3][0].x) * c1.z + H2F(kh[3][0].y) * r1
            + H2F(kh[3][1].x) * c0.w + H2F(kh[3][1].y) * c0.z
            + H2F(kh[3][2].x) * r0   + H2F(kh[3][2].y) * c2.w
            + H2F(kh[3][3].x) * c2.z + H2F(kh[3][3].y) * r2;
      *reinterpret_cast<float4*>(Xn + base) = acc;
      c1 = acc;
    }
    __syncthreads();
  }

  // ---- write 32x32 tile (step-6 result is in buf0; T even) ----
  float* yb = xout + (size_t)b * HW;
  int i  = tid >> 4;               // 0..31
  int pj = (tid & 15) * 2;         // 0..30
  float2 v = *reinterpret_cast<const float2*>(sX + (i + T) * XR + (pj + T));
  *reinterpret_cast<float2*>(yb + (size_t)(ti0 + i) * W + (tj0 + pj)) = v;
}

extern "C" void kernel_launch(void* const* d_in, const int* in_sizes, int n_in,
                              void* d_out, int out_size, void* d_ws,
                              size_t ws_size, hipStream_t stream) {
  const float* x  = (const float*)d_in[0];
  const float* Wa = (const float*)d_in[1];
  const float* ba = (const float*)d_in[2];
  float* out = (float*)d_out;

  __half* Kh = (__half*)d_ws;                   // 8N halves = 33.5 MB
  float* xa = (float*)d_ws + 4 * (size_t)N;     // after 16N bytes
  cspn_gen_kernel<<<dim3(N / 4 / 256), dim3(256), 0, stream>>>(x, Wa, ba, Kh);

  const float* src = x;
  for (int l = 0; l < 24 / T; ++l) {   // 4 launches of 6 fused steps
    float* dst = (l & 1) ? out : xa;   // l=3 (odd) -> final lands in d_out
    cspn_fused<<<dim3(NTILES), dim3(NT), 0, stream>>>(src, Kh, dst);
    src = dst;
  }
}

// Round 14
// 129.912 us; speedup vs baseline: 1.1386x; 1.1386x over previous
//
#include <hip/hip_runtime.h>
#include <hip/hip_fp16.h>

// CSPN: affinity conv -> 8 a-planes fp16 AoS (16 B/px) -> 24 diffusion steps
// fused T=6/launch. Fused kernel = round-11 winner verbatim ((512,6), 4-px
// threads, c1 register carry). Gen kernel vectorized 4 px/thread.
constexpr int B = 8, H = 512, W = 512;
constexpr int N = B * H * W;       // 2,097,152
constexpr int HW = H * W;

constexpr int TT = 32;             // output tile side
constexpr int T  = 6;              // fused steps per launch (24 = 4*6)
constexpr int XR = TT + 2 * T;     // 44: staged X region side
constexpr int XE = XR * XR;        // 1936 floats per buffer
constexpr int NG = XR / 4;         // 11 col-groups per row
constexpr int CR = XR - 2;         // 42 computed rows (xi = 1..42)
constexpr int NGT = CR * NG;       // 462 active threads
constexpr int NTH = H / TT, NTW = W / TT;   // 16 x 16
constexpr int NTILES = B * NTH * NTW;       // 2048 (div by 8 -> bijective swz)
constexpr int NT = 512;

// ---------------------------------------------------------------------------
// Kernel 1: affinity conv (1->8, 3x3 SAME) + bias -> normalize -> fp16 AoS.
// 4 px/thread: rows i-1..i+1 x cols j0-1..j0+4 loaded as float4 + 2 scalars.
// ---------------------------------------------------------------------------
__global__ __launch_bounds__(256) void cspn_gen_kernel(
    const float* __restrict__ x, const float* __restrict__ Wa,
    const float* __restrict__ ba, __half* __restrict__ Kh) {
  int t = blockIdx.x * 256 + threadIdx.x;     // N/4 threads
  int j0 = (t & (W / 4 - 1)) * 4;             // 0..508 step 4
  int i  = (t >> 7) & (H - 1);
  int b  = t >> 16;
  const float* xb = x + (size_t)b * HW;

  float rv[3][6];
#pragma unroll
  for (int r = 0; r < 3; ++r) {
    int ii = i - 1 + r;
    if ((unsigned)ii < (unsigned)H) {
      const float* row = xb + (size_t)ii * W;
      float4 c = *reinterpret_cast<const float4*>(row + j0);
      rv[r][1] = c.x; rv[r][2] = c.y; rv[r][3] = c.z; rv[r][4] = c.w;
      rv[r][0] = (j0 > 0) ? row[j0 - 1] : 0.f;
      rv[r][5] = (j0 + 4 < W) ? row[j0 + 4] : 0.f;
    } else {
#pragma unroll
      for (int q = 0; q < 6; ++q) rv[r][q] = 0.f;
    }
  }

  __half* Kp = Kh + ((size_t)b * HW + (size_t)i * W + j0) * 8;
#pragma unroll
  for (int p = 0; p < 4; ++p) {
    float aff[8];
    float abs_sum = 0.f;
#pragma unroll
    for (int c = 0; c < 8; ++c) {
      float a = ba[c];
#pragma unroll
      for (int u = 0; u < 3; ++u)
#pragma unroll
        for (int q = 0; q < 3; ++q)
          a += rv[u][p + q] * Wa[c * 9 + u * 3 + q];
      aff[c] = a;
      abs_sum += fabsf(a);
    }
    float inv = 1.0f / abs_sum;
    union { uint4 u; __half2 h[4]; } pk;
#pragma unroll
    for (int c = 0; c < 4; ++c)
      pk.h[c] = __floats2half2_rn(aff[2 * c] * inv, aff[2 * c + 1] * inv);
    *reinterpret_cast<uint4*>(Kp + (size_t)p * 8) = pk.u;
  }
}

// ---------------------------------------------------------------------------
// Kernel 2: T=6 fused steps, 32x32 tile, X region 44x44 double-buffered.
// Round-11 winner verbatim: thread owns 4-px group (xi, xj0..+3); K packed
// fp16 (16 half2 + 4 fp32 K0); own 4 px ride in c1. launch_bounds(512,6):
// 3 blocks/CU, no spill (measured 119.3 us total in round 11).
// ---------------------------------------------------------------------------
#define H2F(h) __half2float(h)

__global__ __launch_bounds__(NT, 6) void cspn_fused(
    const float* __restrict__ xin, const __half* __restrict__ Kh,
    float* __restrict__ xout) {
  __shared__ __align__(16) float sBuf[64 + 2 * XE + 64];  // front/back guards
  float* sX = sBuf + 64;

  int bid = blockIdx.x;
  int wg = (bid & 7) * (NTILES / 8) + (bid >> 3);  // XCD-chunked swizzle
  int b  = wg / (NTH * NTW);
  int rr = wg % (NTH * NTW);
  int ti0 = (rr / NTW) * TT, tj0 = (rr % NTW) * TT;
  int tid = threadIdx.x;

  bool active = tid < NGT;
  int xi  = 1 + tid / NG;          // 1..42
  int xj0 = (tid % NG) * 4;        // 0,4,...,40

  // ---- one-time K fragment: 4 px x half8, kept PACKED (16 half2 regs) ----
  __half2 kh[4][4];                // [px][tap-pair]
  float4 k0;                       // fp32 center tap per px
  {
    int gi  = ti0 + xi - T;
    int gj0 = tj0 + xj0 - T;
    bool rowv = active && (unsigned)gi < (unsigned)H;
    const __half* Kb =
        Kh + ((size_t)b * HW + (size_t)(rowv ? gi : 0) * W) * 8;
    float k0v[4];
#pragma unroll
    for (int p = 0; p < 4; ++p) {
      int gj = gj0 + p;
      union { uint4 u; __half2 h[4]; } pk;
      pk.u = make_uint4(0u, 0u, 0u, 0u);
      if (rowv && (unsigned)gj < (unsigned)W)
        pk.u = *reinterpret_cast<const uint4*>(Kb + (size_t)gj * 8);
      float2 f01 = __half22float2(pk.h[0]);
      float2 f23 = __half22float2(pk.h[1]);
      float2 f45 = __half22float2(pk.h[2]);
      float2 f67 = __half22float2(pk.h[3]);
      k0v[p] = 1.0f - (f01.x + f01.y + f23.x + f23.y +
                       f45.x + f45.y + f67.x + f67.y);
      kh[p][0] = pk.h[0]; kh[p][1] = pk.h[1];
      kh[p][2] = pk.h[2]; kh[p][3] = pk.h[3];
    }
    k0 = make_float4(k0v[0], k0v[1], k0v[2], k0v[3]);
  }

  // ---- zero LDS guards + buf1 border rows (never computed) ----
  if (tid < 64) {
    sBuf[tid] = 0.f;
    sBuf[64 + 2 * XE + tid] = 0.f;
  }
  if (tid < 2 * XR) {              // buf1 rows 0 and 43
    int r = (tid < XR) ? 0 : (XR - 1);
    int c = (tid < XR) ? tid : tid - XR;
    sX[XE + r * XR + c] = 0.f;
  }

  // ---- stage X region into buf0 (float2-vectorized) ----
  const float* xb = xin + (size_t)b * HW;
  for (int p = tid; p < XR * (XR / 2); p += NT) {   // 968 float2
    int li = p / (XR / 2), g = p - li * (XR / 2);
    int gi = ti0 + li - T, gj = tj0 + 2 * g - T;
    float2 v = make_float2(0.f, 0.f);
    if ((unsigned)gi < (unsigned)H && (unsigned)gj < (unsigned)W)
      v = *reinterpret_cast<const float2*>(xb + gi * W + gj);
    *reinterpret_cast<float2*>(sX + li * XR + 2 * g) = v;
  }
  __syncthreads();

  // ---- T fused steps; own 4 px live in c1 ----
  int base = xi * XR + xj0;
  float4 c1;
  if (active) c1 = *reinterpret_cast<const float4*>(sX + base);
#pragma unroll
  for (int s = 0; s < T; ++s) {
    const float* Xc = sX + (s & 1) * XE;
    float* Xn = sX + (((s & 1) ^ 1)) * XE;
    if (active) {
      const float* rm = Xc + base - XR;
      const float* rp = Xc + base + XR;
      float4 c0 = *reinterpret_cast<const float4*>(rm);
      float  l0 = rm[-1], r0 = rm[4];
      float4 c2 = *reinterpret_cast<const float4*>(rp);
      float  l2 = rp[-1], r2 = rp[4];
      float  l1 = Xc[base - 1], r1 = Xc[base + 4];
      float4 acc;
      acc.x = k0.x * c1.x
            + H2F(kh[0][0].x) * l1   + H2F(kh[0][0].y) * c1.y
            + H2F(kh[0][1].x) * c0.x + H2F(kh[0][1].y) * l0
            + H2F(kh[0][2].x) * c0.y + H2F(kh[0][2].y) * c2.x
            + H2F(kh[0][3].x) * l2   + H2F(kh[0][3].y) * c2.y;
      acc.y = k0.y * c1.y
            + H2F(kh[1][0].x) * c1.x + H2F(kh[1][0].y) * c1.z
            + H2F(kh[1][1].x) * c0.y + H2F(kh[1][1].y) * c0.x
            + H2F(kh[1][2].x) * c0.z + H2F(kh[1][2].y) * c2.y
            + H2F(kh[1][3].x) * c2.x + H2F(kh[1][3].y) * c2.z;
      acc.z = k0.z * c1.z
            + H2F(kh[2][0].x) * c1.y + H2F(kh[2][0].y) * c1.w
            + H2F(kh[2][1].x) * c0.z + H2F(kh[2][1].y) * c0.y
            + H2F(kh[2][2].x) * c0.w + H2F(kh[2][2].y) * c2.z
            + H2F(kh[2][3].x) * c2.y + H2F(kh[2][3].y) * c2.w;
      acc.w = k0.w * c1.w
            + H2F(kh[3][0].x) * c1.z + H2F(kh[3][0].y) * r1
            + H2F(kh[3][1].x) * c0.w + H2F(kh[3][1].y) * c0.z
            + H2F(kh[3][2].x) * r0   + H2F(kh[3][2].y) * c2.w
            + H2F(kh[3][3].x) * c2.z + H2F(kh[3][3].y) * r2;
      *reinterpret_cast<float4*>(Xn + base) = acc;
      c1 = acc;
    }
    __syncthreads();
  }

  // ---- write 32x32 tile (step-6 result is in buf0; T even) ----
  float* yb = xout + (size_t)b * HW;
  int i  = tid >> 4;               // 0..31
  int pj = (tid & 15) * 2;         // 0..30
  float2 v = *reinterpret_cast<const float2*>(sX + (i + T) * XR + (pj + T));
  *reinterpret_cast<float2*>(yb + (size_t)(ti0 + i) * W + (tj0 + pj)) = v;
}

extern "C" void kernel_launch(void* const* d_in, const int* in_sizes, int n_in,
                              void* d_out, int out_size, void* d_ws,
                              size_t ws_size, hipStream_t stream) {
  const float* x  = (const float*)d_in[0];
  const float* Wa = (const float*)d_in[1];
  const float* ba = (const float*)d_in[2];
  float* out = (float*)d_out;

  __half* Kh = (__half*)d_ws;                   // 8N halves = 33.5 MB
  float* xa = (float*)d_ws + 4 * (size_t)N;     // after 16N bytes
  cspn_gen_kernel<<<dim3(N / 4 / 256), dim3(256), 0, stream>>>(x, Wa, ba, Kh);

  const float* src = x;
  for (int l = 0; l < 24 / T; ++l) {   // 4 launches of 6 fused steps
    float* dst = (l & 1) ? out : xa;   // l=3 (odd) -> final lands in d_out
    cspn_fused<<<dim3(NTILES), dim3(NT), 0, stream>>>(src, Kh, dst);
    src = dst;
  }
}

// Round 15
// 115.123 us; speedup vs baseline: 1.2849x; 1.1285x over previous
//
#include <hip/hip_runtime.h>
#include <hip/hip_fp16.h>

// CSPN: affinity conv -> 8 a-planes fp16 AoS (16 B/px) -> 24 diffusion steps
// fused T=6/launch. Fused = round-11 structure + ds_read2 edge pairs +
// stage-loads-before-K-loads. Gen = round-11 scalar (measured good; the
// round-13/14 vectorized gen was ~10us SLOWER - reverted).
constexpr int B = 8, H = 512, W = 512;
constexpr int N = B * H * W;       // 2,097,152
constexpr int HW = H * W;

constexpr int TT = 32;             // output tile side
constexpr int T  = 6;              // fused steps per launch (24 = 4*6)
constexpr int XR = TT + 2 * T;     // 44: staged X region side
constexpr int XE = XR * XR;        // 1936 floats per buffer
constexpr int NG = XR / 4;         // 11 col-groups per row
constexpr int CR = XR - 2;         // 42 computed rows (xi = 1..42)
constexpr int NGT = CR * NG;       // 462 active threads
constexpr int NTH = H / TT, NTW = W / TT;   // 16 x 16
constexpr int NTILES = B * NTH * NTW;       // 2048 (div by 8 -> bijective swz)
constexpr int NT = 512;
constexpr int NF2 = XR * (XR / 2); // 968 float2 to stage

// ---------------------------------------------------------------------------
// Kernel 1: affinity conv (1->8, 3x3 SAME) + bias -> normalize -> fp16 AoS.
// Scalar 1 px/thread (round-11 version, measured ~15us; vectorized variant
// regressed ~10us in rounds 13/14 - do not re-introduce without disasm).
// ---------------------------------------------------------------------------
__global__ __launch_bounds__(256) void cspn_gen_kernel(
    const float* __restrict__ x, const float* __restrict__ Wa,
    const float* __restrict__ ba, __half* __restrict__ Kh) {
  int idx = blockIdx.x * 256 + threadIdx.x;
  if (idx >= N) return;
  int j = idx & (W - 1);
  int i = (idx >> 9) & (H - 1);
  const float* xb = x + (idx & ~(HW - 1));

  float v[9];
#pragma unroll
  for (int u = 0; u < 3; ++u) {
#pragma unroll
    for (int t = 0; t < 3; ++t) {
      int ii = i + u - 1, jj = j + t - 1;
      v[u * 3 + t] = (unsigned(ii) < (unsigned)H && unsigned(jj) < (unsigned)W)
                         ? xb[ii * W + jj]
                         : 0.0f;
    }
  }

  float aff[8];
  float abs_sum = 0.0f;
#pragma unroll
  for (int c = 0; c < 8; ++c) {
    float a = ba[c];
#pragma unroll
    for (int t = 0; t < 9; ++t) a += v[t] * Wa[c * 9 + t];
    aff[c] = a;
    abs_sum += fabsf(a);
  }
  float inv = 1.0f / abs_sum;
#pragma unroll
  for (int c = 0; c < 8; ++c) aff[c] *= inv;

  union { uint4 u; __half2 h[4]; } pk;
#pragma unroll
  for (int c = 0; c < 4; ++c)
    pk.h[c] = __floats2half2_rn(aff[2 * c], aff[2 * c + 1]);
  *reinterpret_cast<uint4*>(Kh + (size_t)idx * 8) = pk.u;
}

// ---------------------------------------------------------------------------
// Kernel 2: T=6 fused steps, 32x32 tile, X region 44x44 double-buffered.
// Thread owns 4-px group (xi, xj0..+3); K packed fp16 (16 half2 + 4 fp32 K0);
// own 4 px ride in c1. Edge scalars read as read2 pairs (base, offs 0/5).
// launch_bounds(512,6): 3 blocks/CU, no spill.
// ---------------------------------------------------------------------------
#define H2F(h) __half2float(h)

__global__ __launch_bounds__(NT, 6) void cspn_fused(
    const float* __restrict__ xin, const __half* __restrict__ Kh,
    float* __restrict__ xout) {
  __shared__ __align__(16) float sBuf[64 + 2 * XE + 64];  // front/back guards
  float* sX = sBuf + 64;

  int bid = blockIdx.x;
  int wg = (bid & 7) * (NTILES / 8) + (bid >> 3);  // XCD-chunked swizzle
  int b  = wg / (NTH * NTW);
  int rr = wg % (NTH * NTW);
  int ti0 = (rr / NTW) * TT, tj0 = (rr % NTW) * TT;
  int tid = threadIdx.x;

  bool active = tid < NGT;
  int xi  = 1 + tid / NG;          // 1..42
  int xj0 = (tid % NG) * 4;        // 0,4,...,40

  const float* xb = xin + (size_t)b * HW;

  // ---- issue staging loads FIRST (latency overlaps K load+unpack) ----
  int li0 = tid / (XR / 2), gc0 = tid - li0 * (XR / 2);
  int p1 = tid + NT;
  int li1 = p1 / (XR / 2), gc1 = p1 - li1 * (XR / 2);
  bool st1 = p1 < NF2;
  float2 sv0 = make_float2(0.f, 0.f), sv1 = make_float2(0.f, 0.f);
  {
    int gi = ti0 + li0 - T, gj = tj0 + 2 * gc0 - T;
    if ((unsigned)gi < (unsigned)H && (unsigned)gj < (unsigned)W)
      sv0 = *reinterpret_cast<const float2*>(xb + gi * W + gj);
  }
  if (st1) {
    int gi = ti0 + li1 - T, gj = tj0 + 2 * gc1 - T;
    if ((unsigned)gi < (unsigned)H && (unsigned)gj < (unsigned)W)
      sv1 = *reinterpret_cast<const float2*>(xb + gi * W + gj);
  }

  // ---- one-time K fragment: 4 px x half8, kept PACKED (16 half2 regs) ----
  __half2 kh[4][4];                // [px][tap-pair]
  float4 k0;                       // fp32 center tap per px
  {
    int gi  = ti0 + xi - T;
    int gj0 = tj0 + xj0 - T;
    bool rowv = active && (unsigned)gi < (unsigned)H;
    const __half* Kb =
        Kh + ((size_t)b * HW + (size_t)(rowv ? gi : 0) * W) * 8;
    float k0v[4];
#pragma unroll
    for (int p = 0; p < 4; ++p) {
      int gj = gj0 + p;
      union { uint4 u; __half2 h[4]; } pk;
      pk.u = make_uint4(0u, 0u, 0u, 0u);
      if (rowv && (unsigned)gj < (unsigned)W)
        pk.u = *reinterpret_cast<const uint4*>(Kb + (size_t)gj * 8);
      float2 f01 = __half22float2(pk.h[0]);
      float2 f23 = __half22float2(pk.h[1]);
      float2 f45 = __half22float2(pk.h[2]);
      float2 f67 = __half22float2(pk.h[3]);
      k0v[p] = 1.0f - (f01.x + f01.y + f23.x + f23.y +
                       f45.x + f45.y + f67.x + f67.y);
      kh[p][0] = pk.h[0]; kh[p][1] = pk.h[1];
      kh[p][2] = pk.h[2]; kh[p][3] = pk.h[3];
    }
    k0 = make_float4(k0v[0], k0v[1], k0v[2], k0v[3]);
  }

  // ---- write staged values to LDS buf0; zero guards + buf1 border rows ----
  *reinterpret_cast<float2*>(sX + li0 * XR + 2 * gc0) = sv0;
  if (st1) *reinterpret_cast<float2*>(sX + li1 * XR + 2 * gc1) = sv1;
  if (tid < 64) {
    sBuf[tid] = 0.f;
    sBuf[64 + 2 * XE + tid] = 0.f;
  }
  if (tid < 2 * XR) {              // buf1 rows 0 and 43
    int r = (tid < XR) ? 0 : (XR - 1);
    int c = (tid < XR) ? tid : tid - XR;
    sX[XE + r * XR + c] = 0.f;
  }
  __syncthreads();

  // ---- T fused steps; own 4 px live in c1 ----
  int base = xi * XR + xj0;
  float4 c1;
  if (active) c1 = *reinterpret_cast<const float4*>(sX + base);
#pragma unroll
  for (int s = 0; s < T; ++s) {
    const float* Xc = sX + (s & 1) * XE;
    float* Xn = sX + (((s & 1) ^ 1)) * XE;
    if (active) {
      // edge-pair bases: offsets 0 and 5 -> ds_read2_b32
      const float* eu = Xc + base - XR - 1;
      const float* ec = Xc + base - 1;
      const float* ed = Xc + base + XR - 1;
      float l0 = eu[0], r0 = eu[5];
      float l1 = ec[0], r1 = ec[5];
      float l2 = ed[0], r2 = ed[5];
      float4 c0 = *reinterpret_cast<const float4*>(eu + 1);  // base-XR, 16B al.
      float4 c2 = *reinterpret_cast<const float4*>(ed + 1);  // base+XR, 16B al.
      float4 acc;
      acc.x = k0.x * c1.x
            + H2F(kh[0][0].x) * l1   + H2F(kh[0][0].y) * c1.y
            + H2F(kh[0][1].x) * c0.x + H2F(kh[0][1].y) * l0
            + H2F(kh[0][2].x) * c0.y + H2F(kh[0][2].y) * c2.x
            + H2F(kh[0][3].x) * l2   + H2F(kh[0][3].y) * c2.y;
      acc.y = k0.y * c1.y
            + H2F(kh[1][0].x) * c1.x + H2F(kh[1][0].y) * c1.z
            + H2F(kh[1][1].x) * c0.y + H2F(kh[1][1].y) * c0.x
            + H2F(kh[1][2].x) * c0.z + H2F(kh[1][2].y) * c2.y
            + H2F(kh[1][3].x) * c2.x + H2F(kh[1][3].y) * c2.z;
      acc.z = k0.z * c1.z
            + H2F(kh[2][0].x) * c1.y + H2F(kh[2][0].y) * c1.w
            + H2F(kh[2][1].x) * c0.z + H2F(kh[2][1].y) * c0.y
            + H2F(kh[2][2].x) * c0.w + H2F(kh[2][2].y) * c2.z
            + H2F(kh[2][3].x) * c2.y + H2F(kh[2][3].y) * c2.w;
      acc.w = k0.w * c1.w
            + H2F(kh[3][0].x) * c1.z + H2F(kh[3][0].y) * r1
            + H2F(kh[3][1].x) * c0.w + H2F(kh[3][1].y) * c0.z
            + H2F(kh[3][2].x) * r0   + H2F(kh[3][2].y) * c2.w
            + H2F(kh[3][3].x) * c2.z + H2F(kh[3][3].y) * r2;
      *reinterpret_cast<float4*>(Xn + base) = acc;
      c1 = acc;
    }
    __syncthreads();
  }

  // ---- write 32x32 tile (step-6 result is in buf0; T even) ----
  float* yb = xout + (size_t)b * HW;
  int i  = tid >> 4;               // 0..31
  int pj = (tid & 15) * 2;         // 0..30
  float2 v = *reinterpret_cast<const float2*>(sX + (i + T) * XR + (pj + T));
  *reinterpret_cast<float2*>(yb + (size_t)(ti0 + i) * W + (tj0 + pj)) = v;
}

extern "C" void kernel_launch(void* const* d_in, const int* in_sizes, int n_in,
                              void* d_out, int out_size, void* d_ws,
                              size_t ws_size, hipStream_t stream) {
  const float* x  = (const float*)d_in[0];
  const float* Wa = (const float*)d_in[1];
  const float* ba = (const float*)d_in[2];
  float* out = (float*)d_out;

  __half* Kh = (__half*)d_ws;                   // 8N halves = 33.5 MB
  float* xa = (float*)d_ws + 4 * (size_t)N;     // after 16N bytes
  cspn_gen_kernel<<<dim3(N / 256), dim3(256), 0, stream>>>(x, Wa, ba, Kh);

  const float* src = x;
  for (int l = 0; l < 24 / T; ++l) {   // 4 launches of 6 fused steps
    float* dst = (l & 1) ? out : xa;   // l=3 (odd) -> final lands in d_out
    cspn_fused<<<dim3(NTILES), dim3(NT), 0, stream>>>(src, Kh, dst);
    src = dst;
  }
}